// Round 15
// baseline (3365.515 us; speedup 1.0000x reference)
//
#include <hip/hip_runtime.h>

// LSTM B=64 T=512 IN=512 H=1024 OUT=512, all fp32 in/out.
// R14 = R11-BIG (best 2312us) + R13's intent WITHOUT the scheduling poison:
//   - 8 h loads, then 4 x(t+1) prefetch loads (asm -> guaranteed queue order)
//   - x MFMAs for step t run on prefetched regs UNDER h flight
//   - single s_waitcnt vmcnt(4) (+ one rule-#18 sched_barrier, same count as
//     R11) -> h retired, x still flying; epilogue's existing vmcnt(0) ack
//     retires x for free
//   R13's 9 pinned incremental waits (m141 failure mode) removed.

#define B_   64
#define T_   512
#define IN_  512
#define H_   1024
#define G4_  4096   // 4*H
#define OUT_ 512

typedef _Float16 f16;
typedef _Float16 f16x8 __attribute__((ext_vector_type(8)));
typedef _Float16 f16x4 __attribute__((ext_vector_type(4)));
typedef float f32x4  __attribute__((ext_vector_type(4)));
typedef float f32x16 __attribute__((ext_vector_type(16)));

// workspace layout (bytes)
#define X16_OFF   0UL                          // [64][512][512] f16 = 33554432
#define WOT_OFF   33554432UL                   // W_out^T f16 = 1048576
#define HS_OFF    34603008UL                   // small h dbuf [2g][2][32][1024] f16
#define FLG_OFF   34865152UL                   // flags [2g][64][8] u32 = 4096
#define WS_SMALL  34869248UL
#define HBIG_OFF  35135488UL                   // h history [513][2][32][1024] f16
#define HBIG_BYTES (513UL * 2 * 32 * 1024 * 2) // 67239936
#define WS_BIG    (HBIG_OFF + HBIG_BYTES)      // ~102.4MB

__device__ __forceinline__ float sigmoidf_(float v) { return 1.f / (1.f + __expf(-v)); }
__device__ __forceinline__ float tanhf_(float v) { return 1.f - 2.f / (__expf(2.f * v) + 1.f); }

// Agent-coherent load (bypass L1+L2; LLC point) — small-path h loads.
__device__ __forceinline__ f16x8 ld_agent_b128(const f16* p) {
  f16x8 r;
  asm volatile("global_load_dwordx4 %0, %1, off sc0 sc1" : "=v"(r) : "v"(p));
  return r;
}
// Cached load (L1+L2 allocate) — BIG-path h loads and x prefetch.
__device__ __forceinline__ f16x8 ld_cached_b128(const f16* p) {
  f16x8 r;
  asm volatile("global_load_dwordx4 %0, %1, off" : "=v"(r) : "v"(p));
  return r;
}
// Write-through 4B store to the LLC coherence point.
__device__ __forceinline__ void st_agent_b32(unsigned* p, unsigned v) {
  asm volatile("global_store_dword %0, %1, off sc0 sc1" :: "v"(p), "v"(v) : "memory");
}
__device__ __forceinline__ unsigned ld_flag(const unsigned* p) {
  unsigned r;
  asm volatile("global_load_dword %0, %1, off sc0 sc1" : "=v"(r) : "v"(p));
  return r;
}
__device__ __forceinline__ void wait_vm0() {
  asm volatile("s_waitcnt vmcnt(0)" ::: "memory");
  __builtin_amdgcn_sched_barrier(0);
}
__device__ __forceinline__ void wait_vm1() {
  asm volatile("s_waitcnt vmcnt(1)" ::: "memory");
  __builtin_amdgcn_sched_barrier(0);
}
__device__ __forceinline__ void wait_vm4() {
  asm volatile("s_waitcnt vmcnt(4)" ::: "memory");
  __builtin_amdgcn_sched_barrier(0);
}

__global__ __launch_bounds__(256) void lstm_prepass(
    const float* __restrict__ x, const float* __restrict__ Wout,
    f16* __restrict__ x16, f16* __restrict__ WoT) {
  long i = (long)blockIdx.x * blockDim.x + threadIdx.x;
  long stride = (long)gridDim.x * blockDim.x;
  const long n4 = (long)B_ * T_ * IN_ / 4;
  const float4* x4 = (const float4*)x;
  f16x4* o4 = (f16x4*)x16;
  for (long p = i; p < n4; p += stride) {
    float4 v = x4[p];
    f16x4 o = { (f16)v.x, (f16)v.y, (f16)v.z, (f16)v.w };
    o4[p] = o;
  }
  const long nw = (long)H_ * OUT_;
  for (long p = i; p < nw; p += stride) {
    long k = p / OUT_, c = p % OUT_;
    WoT[c * (long)H_ + k] = (f16)Wout[p];
  }
}

// 128 WGs x 512 threads (8 waves). WG wg: group g = wg>>6 (rows g*32..g*32+31),
// wgi = wg&63 owns h-cols [wgi*16, wgi*16+16). 8 waves K-split K=1536
// (x 64/wave, h 128/wave). Wave w's h K-range produced by slots 8w..8w+7;
// per-(slot,wave) flags.
template<bool BIG>
__global__ __launch_bounds__(512, 2) void lstm_main(
    const float* __restrict__ W, const float* __restrict__ b,
    const f16* __restrict__ x16, f16* hbuf, unsigned* flags) {

  const int wg   = blockIdx.x;
  const int g    = wg >> 6;
  const int wgi  = wg & 63;
  const int tid  = threadIdx.x;
  const int wave = tid >> 6;    // 0..7
  const int lane = tid & 63;

  const int cbase   = wgi * 16;
  const int colLane = lane & 31;
  const int khalf   = (lane >> 5) * 8;
  const int arow    = lane & 31;

  // ---- persistent W fragments (fp32 -> fp16, MFMA B layout) ----
  f16x8 wf[24];
  #pragma unroll
  for (int n = 0; n < 2; ++n) {
    const int gate = n * 2 + (colLane >> 4);
    const int gcol = gate * H_ + cbase + (colLane & 15);
    #pragma unroll
    for (int kf = 0; kf < 12; ++kf) {
      const int k0 = (kf < 4) ? (64 * wave + 16 * kf)
                              : (512 + 128 * wave + 16 * (kf - 4));
      f16x8 v;
      #pragma unroll
      for (int j = 0; j < 8; ++j)
        v[j] = (f16)W[(long)(k0 + khalf + j) * G4_ + gcol];
      wf[n * 12 + kf] = v;
    }
  }

  const int erow = tid >> 4;
  const int ej   = tid & 15;
  float bias[4];
  #pragma unroll
  for (int gt = 0; gt < 4; ++gt) bias[gt] = b[gt * H_ + cbase + ej];

  float c_state = 0.f;

  __shared__ float red[2][8][32][68];

  const f16* xg = x16 + (long)(g * 32) * T_ * IN_;
  unsigned* flg = flags + g * 64 * 8;

  const unsigned* fp = flg + 64 * wave + lane;
  unsigned* myflag = flg + wgi * 8 + wave;

  auto hrd = [&](int t) -> const f16* {
    if constexpr (BIG) return hbuf + ((long)t * 2 + g) * (32 * H_);
    else               return hbuf + ((long)g * 2 + (t & 1)) * (32 * H_);
  };
  auto hwr = [&](int t) -> f16* {
    if constexpr (BIG) return hbuf + ((long)(t + 1) * 2 + g) * (32 * H_);
    else               return hbuf + ((long)g * 2 + ((t + 1) & 1)) * (32 * H_);
  };

  // ---- prologue: prefetch x(0) into regs ----
  f16x8 xa[4], xn[4];
  {
    const f16* xrow = xg + (long)arow * (T_ * IN_) + 64 * wave + khalf;
    #pragma unroll
    for (int f = 0; f < 4; ++f) xa[f] = ld_cached_b128(xrow + 16 * f);
  }
  wait_vm0();

  for (int t = 0; t < T_; ++t) {
    // ---- poll: my 64 producer-wave flags >= t (ends with vmcnt(0) drain,
    //      which also retires the x(t) prefetch from the previous iter) ----
    if (t > 0) {
      const unsigned tgt = (unsigned)t;
      int guard = 0;
      unsigned v0 = ld_flag(fp);
      unsigned v1 = 0;
      for (;;) {
        v1 = ld_flag(fp);
        wait_vm1();
        if (__all(v0 >= tgt) || ++guard > (1 << 22)) break;
        v0 = ld_flag(fp);
        wait_vm1();
        if (__all(v1 >= tgt) || ++guard > (1 << 22)) break;
      }
      asm volatile("s_waitcnt vmcnt(0)" ::: "memory");
      asm volatile("" :: "v"(v0), "v"(v1));
      __builtin_amdgcn_sched_barrier(0);
    }

    // ---- issue 8 h loads, then 4 x(t+1) prefetch loads (queue order) ----
    f16x8 ha[8];
    {
      const f16* hrow = hrd(t) + (long)arow * H_ + 128 * wave + khalf;
      #pragma unroll
      for (int f = 0; f < 8; ++f)
        ha[f] = BIG ? ld_cached_b128(hrow + 16 * f)
                    : ld_agent_b128(hrow + 16 * f);
    }
    {
      const int tx = (t + 1 < T_) ? (t + 1) : (T_ - 1);  // clamp; last unused
      const f16* xrow = xg + (long)arow * (T_ * IN_) + (long)tx * IN_
                           + 64 * wave + khalf;
      #pragma unroll
      for (int f = 0; f < 4; ++f) xn[f] = ld_cached_b128(xrow + 16 * f);
    }

    // ---- x MFMAs for step t (xa in regs): execute under h-load flight ----
    f32x16 acc0 = {}, acc1 = {};
    #pragma unroll
    for (int kf = 0; kf < 4; ++kf) {
      acc0 = __builtin_amdgcn_mfma_f32_32x32x16_f16(xa[kf], wf[kf],      acc0, 0, 0, 0);
      acc1 = __builtin_amdgcn_mfma_f32_32x32x16_f16(xa[kf], wf[12 + kf], acc1, 0, 0, 0);
    }

    // ---- single wait: h retired (4 x loads may still be in flight) ----
    wait_vm4();

    // ---- h MFMAs ----
    #pragma unroll
    for (int kf = 0; kf < 8; ++kf) {
      acc0 = __builtin_amdgcn_mfma_f32_32x32x16_f16(ha[kf], wf[4 + kf],  acc0, 0, 0, 0);
      acc1 = __builtin_amdgcn_mfma_f32_32x32x16_f16(ha[kf], wf[16 + kf], acc1, 0, 0, 0);
    }

    // ---- cross-wave K-reduction via LDS (double-buffered) ----
    {
      float (*rb)[32][68] = red[t & 1];
      #pragma unroll
      for (int r = 0; r < 16; ++r) {
        const int row = (r & 3) + 8 * (r >> 2) + 4 * (lane >> 5);
        rb[wave][row][colLane]      = acc0[r];
        rb[wave][row][32 + colLane] = acc1[r];
      }
    }
    __syncthreads();   // the only barrier per step

    // ---- epilogue: gates, c/h update, paired write-through publish ----
    {
      const float (*rb)[32][68] = red[t & 1];
      float f4[4];
      #pragma unroll
      for (int gt = 0; gt < 4; ++gt) {
        float s = bias[gt];
        #pragma unroll
        for (int w = 0; w < 8; ++w) s += rb[w][erow][gt * 16 + ej];
        f4[gt] = s;
      }
      const float fg = sigmoidf_(f4[0]);
      const float ig = sigmoidf_(f4[1]);
      const float gg = tanhf_(f4[2]);
      const float og = sigmoidf_(f4[3]);
      c_state = c_state * fg + ig * gg;
      const float hv = og * tanhf_(c_state);

      const unsigned h16 =
          (unsigned)__builtin_bit_cast(unsigned short, (f16)hv);
      const unsigned hi = (unsigned)__shfl_xor((int)h16, 1, 64);
      if ((lane & 1) == 0) {
        unsigned pk = h16 | (hi << 16);
        unsigned* p = (unsigned*)(hwr(t) + (long)erow * H_ + cbase + ej);
        st_agent_b32(p, pk);
      }
      wait_vm0();   // ack h stores (x prefetch ~1us old -> already retired)
      if (lane == 0)
        st_agent_b32(myflag, (unsigned)(t + 1));
    }

    // ---- rotate x prefetch regs ----
    #pragma unroll
    for (int f = 0; f < 4; ++f) xa[f] = xn[f];
  }
}

// out = h_T @ W_out + b_out. hT = base ptr to [g][32][1024] (gs = group stride).
__global__ __launch_bounds__(256) void lstm_out(
    const f16* __restrict__ hT, long gs, const f16* __restrict__ WoT,
    const float* __restrict__ bout, float* __restrict__ out) {
  const int wgid = blockIdx.x;
  const int rowT = wgid >> 5;
  const int colT = wgid & 31;
  const int tid  = threadIdx.x;
  const int wave = tid >> 6;
  const int lane = tid & 63;
  const int r16  = lane & 15;
  const int ksel = (lane >> 4) * 8;

  const int g = rowT >> 1;
  const f16* hrow = hT + (long)g * gs + (long)((rowT & 1) * 16 + r16) * H_;
  const f16* wrow = WoT + (long)(colT * 16 + r16) * H_;

  f32x4 acc = {};
  #pragma unroll
  for (int f = 0; f < 8; ++f) {
    f16x8 a  = *(const f16x8*)(hrow + 256 * wave + 32 * f + ksel);
    f16x8 bf = *(const f16x8*)(wrow + 256 * wave + 32 * f + ksel);
    acc = __builtin_amdgcn_mfma_f32_16x16x32_f16(a, bf, acc, 0, 0, 0);
  }

  __shared__ float red[4][16][20];
  #pragma unroll
  for (int r = 0; r < 4; ++r)
    red[wave][(lane >> 4) * 4 + r][lane & 15] = acc[r];
  __syncthreads();

  const int row = tid >> 4;
  const int col = tid & 15;
  float s = bout[colT * 16 + col];
  #pragma unroll
  for (int w = 0; w < 4; ++w) s += red[w][row][col];
  out[(long)(rowT * 16 + row) * OUT_ + colT * 16 + col] = s;
}

extern "C" void kernel_launch(void* const* d_in, const int* in_sizes, int n_in,
                              void* d_out, int out_size, void* d_ws, size_t ws_size,
                              hipStream_t stream) {
  const float* x    = (const float*)d_in[0];
  const float* W    = (const float*)d_in[1];
  const float* b    = (const float*)d_in[2];
  const float* Wout = (const float*)d_in[3];
  const float* bout = (const float*)d_in[4];
  float* out = (float*)d_out;

  if (ws_size < WS_SMALL) return;

  char* wsb = (char*)d_ws;
  f16* x16  = (f16*)(wsb + X16_OFF);
  f16* WoT  = (f16*)(wsb + WOT_OFF);
  unsigned* flags = (unsigned*)(wsb + FLG_OFF);

  lstm_prepass<<<1024, 256, 0, stream>>>(x, Wout, x16, WoT);

  if (ws_size >= WS_BIG) {
    // BIG: write-once history, cached consumer loads.
    f16* hbig = (f16*)(wsb + HBIG_OFF);
    hipMemsetAsync(wsb + HBIG_OFF, 0, 2 * 32 * H_ * sizeof(f16), stream); // h0
    hipMemsetAsync(wsb + FLG_OFF, 0, 4096, stream);                       // flags
    lstm_main<true><<<128, 512, 0, stream>>>(W, b, x16, hbig, flags);
    lstm_out<<<128, 256, 0, stream>>>(hbig + (long)T_ * 2 * 32 * H_,
                                      (long)32 * H_, WoT, bout, out);
  } else {
    // Fallback: small double-buffer, agent h loads.
    f16* hsm = (f16*)(wsb + HS_OFF);
    hipMemsetAsync(wsb + HS_OFF, 0, FLG_OFF + 4096 - HS_OFF, stream);
    lstm_main<false><<<128, 512, 0, stream>>>(W, b, x16, hsm, flags);
    lstm_out<<<128, 256, 0, stream>>>(hsm, (long)2 * 32 * H_, WoT, bout, out);
  }
}

// Round 16
// 2307.329 us; speedup vs baseline: 1.4586x; 1.4586x over previous
//
#include <hip/hip_runtime.h>

// LSTM B=64 T=512 IN=512 H=1024 OUT=512, all fp32 in/out.
// R15 = R11-BIG (best 2312us; R13/R14 x-prefetch reverted) + vectorized
// cross-wave reduce:
//   - store: red[wave][64col][36row-pad] -> acc row-quads contiguous ->
//     8x ds_write_b128 per thread (was 32x ds_write_b32)
//   - read: lane l of wave w reads red[kw][l][4w..4w+3] kw=0..7 ->
//     8x ds_read_b128 + f32x4 adds (was 32x conflicted ds_read_b32)
//   - in-register 4x4 transpose (4 shfl_xor) redistributes gate quads ->
//     each lane owns (row=4*wave+(lane>>4), hcol=cbase+(lane&15)); c_state
//     per-thread recurrence preserved under the new fixed ownership.
// LDS ops/thread/step: 64 scalar -> 16 vector. Everything else = R11.

#define B_   64
#define T_   512
#define IN_  512
#define H_   1024
#define G4_  4096   // 4*H
#define OUT_ 512

typedef _Float16 f16;
typedef _Float16 f16x8 __attribute__((ext_vector_type(8)));
typedef _Float16 f16x4 __attribute__((ext_vector_type(4)));
typedef float f32x4  __attribute__((ext_vector_type(4)));
typedef float f32x16 __attribute__((ext_vector_type(16)));

// workspace layout (bytes)
#define X16_OFF   0UL                          // [64][512][512] f16 = 33554432
#define WOT_OFF   33554432UL                   // W_out^T f16 = 1048576
#define HS_OFF    34603008UL                   // small h dbuf [2g][2][32][1024] f16
#define FLG_OFF   34865152UL                   // flags [2g][64][8] u32 = 4096
#define WS_SMALL  34869248UL
#define HBIG_OFF  35135488UL                   // h history [513][2][32][1024] f16
#define HBIG_BYTES (513UL * 2 * 32 * 1024 * 2) // 67239936
#define WS_BIG    (HBIG_OFF + HBIG_BYTES)      // ~102.4MB

__device__ __forceinline__ float sigmoidf_(float v) { return 1.f / (1.f + __expf(-v)); }
__device__ __forceinline__ float tanhf_(float v) { return 1.f - 2.f / (__expf(2.f * v) + 1.f); }

// Agent-coherent load (bypass L1+L2; LLC point) — small-path h loads.
__device__ __forceinline__ f16x8 ld_agent_b128(const f16* p) {
  f16x8 r;
  asm volatile("global_load_dwordx4 %0, %1, off sc0 sc1" : "=v"(r) : "v"(p));
  return r;
}
// Cached load (L1+L2 allocate) — BIG-path h loads.
__device__ __forceinline__ f16x8 ld_cached_b128(const f16* p) {
  f16x8 r;
  asm volatile("global_load_dwordx4 %0, %1, off" : "=v"(r) : "v"(p));
  return r;
}
// Write-through 4B store to the LLC coherence point.
__device__ __forceinline__ void st_agent_b32(unsigned* p, unsigned v) {
  asm volatile("global_store_dword %0, %1, off sc0 sc1" :: "v"(p), "v"(v) : "memory");
}
__device__ __forceinline__ unsigned ld_flag(const unsigned* p) {
  unsigned r;
  asm volatile("global_load_dword %0, %1, off sc0 sc1" : "=v"(r) : "v"(p));
  return r;
}
__device__ __forceinline__ void wait_vm0() {
  asm volatile("s_waitcnt vmcnt(0)" ::: "memory");
  __builtin_amdgcn_sched_barrier(0);
}
__device__ __forceinline__ void wait_vm1() {
  asm volatile("s_waitcnt vmcnt(1)" ::: "memory");
  __builtin_amdgcn_sched_barrier(0);
}

__global__ __launch_bounds__(256) void lstm_prepass(
    const float* __restrict__ x, const float* __restrict__ Wout,
    f16* __restrict__ x16, f16* __restrict__ WoT) {
  long i = (long)blockIdx.x * blockDim.x + threadIdx.x;
  long stride = (long)gridDim.x * blockDim.x;
  const long n4 = (long)B_ * T_ * IN_ / 4;
  const float4* x4 = (const float4*)x;
  f16x4* o4 = (f16x4*)x16;
  for (long p = i; p < n4; p += stride) {
    float4 v = x4[p];
    f16x4 o = { (f16)v.x, (f16)v.y, (f16)v.z, (f16)v.w };
    o4[p] = o;
  }
  const long nw = (long)H_ * OUT_;
  for (long p = i; p < nw; p += stride) {
    long k = p / OUT_, c = p % OUT_;
    WoT[c * (long)H_ + k] = (f16)Wout[p];
  }
}

// 128 WGs x 512 threads (8 waves). WG wg: group g = wg>>6 (rows g*32..g*32+31),
// wgi = wg&63 owns h-cols [wgi*16, wgi*16+16). 8 waves K-split K=1536
// (x 64/wave, h 128/wave). Wave w's h K-range produced by slots 8w..8w+7;
// per-(slot,wave) flags. Epilogue ownership: lane l of wave w owns
// (row = 4w + (l>>4), hcol = cbase + (l&15)).
template<bool BIG>
__global__ __launch_bounds__(512, 2) void lstm_main(
    const float* __restrict__ W, const float* __restrict__ b,
    const f16* __restrict__ x16, f16* hbuf, unsigned* flags) {

  const int wg   = blockIdx.x;
  const int g    = wg >> 6;
  const int wgi  = wg & 63;
  const int tid  = threadIdx.x;
  const int wave = tid >> 6;    // 0..7
  const int lane = tid & 63;

  const int cbase   = wgi * 16;
  const int colLane = lane & 31;
  const int khalf   = (lane >> 5) * 8;
  const int arow    = lane & 31;

  // ---- persistent W fragments (fp32 -> fp16, MFMA B layout) ----
  f16x8 wf[24];
  #pragma unroll
  for (int n = 0; n < 2; ++n) {
    const int gate = n * 2 + (colLane >> 4);
    const int gcol = gate * H_ + cbase + (colLane & 15);
    #pragma unroll
    for (int kf = 0; kf < 12; ++kf) {
      const int k0 = (kf < 4) ? (64 * wave + 16 * kf)
                              : (512 + 128 * wave + 16 * (kf - 4));
      f16x8 v;
      #pragma unroll
      for (int j = 0; j < 8; ++j)
        v[j] = (f16)W[(long)(k0 + khalf + j) * G4_ + gcol];
      wf[n * 12 + kf] = v;
    }
  }

  // epilogue ownership: row = 4*wave + (lane>>4), hcol = cbase + ej
  const int erow = 4 * wave + (lane >> 4);
  const int ej   = lane & 15;
  float bias[4];
  #pragma unroll
  for (int gt = 0; gt < 4; ++gt) bias[gt] = b[gt * H_ + cbase + ej];

  float c_state = 0.f;

  // transposed reduce buffer: [dbuf][src wave][64 cols][36 rows-pad] f32
  __shared__ float red[2][8][64][36];   // 144 KB

  const f16* xg = x16 + (long)(g * 32) * T_ * IN_;
  unsigned* flg = flags + g * 64 * 8;

  const unsigned* fp = flg + 64 * wave + lane;
  unsigned* myflag = flg + wgi * 8 + wave;

  auto hrd = [&](int t) -> const f16* {
    if constexpr (BIG) return hbuf + ((long)t * 2 + g) * (32 * H_);
    else               return hbuf + ((long)g * 2 + (t & 1)) * (32 * H_);
  };
  auto hwr = [&](int t) -> f16* {
    if constexpr (BIG) return hbuf + ((long)(t + 1) * 2 + g) * (32 * H_);
    else               return hbuf + ((long)g * 2 + ((t + 1) & 1)) * (32 * H_);
  };

  // ---- x-part of t=0 (h0 = 0 pre-zeroed in ws) ----
  f32x16 acc0 = {}, acc1 = {};
  {
    const f16* xrow = xg + (long)arow * (T_ * IN_) + 64 * wave + khalf;
    f16x8 xa[4];
    #pragma unroll
    for (int f = 0; f < 4; ++f) xa[f] = *(const f16x8*)(xrow + 16 * f);
    #pragma unroll
    for (int kf = 0; kf < 4; ++kf) {
      acc0 = __builtin_amdgcn_mfma_f32_32x32x16_f16(xa[kf], wf[kf],      acc0, 0, 0, 0);
      acc1 = __builtin_amdgcn_mfma_f32_32x32x16_f16(xa[kf], wf[12 + kf], acc1, 0, 0, 0);
    }
  }

  for (int t = 0; t < T_; ++t) {
    // ---- poll: my 64 producer-wave flags >= t ----
    if (t > 0) {
      const unsigned tgt = (unsigned)t;
      int guard = 0;
      unsigned v0 = ld_flag(fp);
      unsigned v1 = 0;
      for (;;) {
        v1 = ld_flag(fp);
        wait_vm1();
        if (__all(v0 >= tgt) || ++guard > (1 << 22)) break;
        v0 = ld_flag(fp);
        wait_vm1();
        if (__all(v1 >= tgt) || ++guard > (1 << 22)) break;
      }
      asm volatile("s_waitcnt vmcnt(0)" ::: "memory");
      asm volatile("" :: "v"(v0), "v"(v1));
      __builtin_amdgcn_sched_barrier(0);
    }

    // ---- h-part: loads of my K-range of h_t ----
    {
      const f16* hrow = hrd(t) + (long)arow * H_ + 128 * wave + khalf;
      f16x8 ha[8];
      #pragma unroll
      for (int f = 0; f < 8; ++f)
        ha[f] = BIG ? ld_cached_b128(hrow + 16 * f)
                    : ld_agent_b128(hrow + 16 * f);
      wait_vm0();
      #pragma unroll
      for (int kf = 0; kf < 8; ++kf) {
        acc0 = __builtin_amdgcn_mfma_f32_32x32x16_f16(ha[kf], wf[4 + kf],  acc0, 0, 0, 0);
        acc1 = __builtin_amdgcn_mfma_f32_32x32x16_f16(ha[kf], wf[16 + kf], acc1, 0, 0, 0);
      }
    }

    // ---- reduce store: transposed, vectorized (8x ds_write_b128) ----
    // acc C layout: col = lane&31, row = (r&3) + 8*(r>>2) + 4*(lane>>5)
    {
      float (*rb)[64][36] = red[t & 1];
      #pragma unroll
      for (int q = 0; q < 4; ++q) {
        const int r0 = 8 * q + 4 * (lane >> 5);
        f32x4 v0 = { acc0[4*q+0], acc0[4*q+1], acc0[4*q+2], acc0[4*q+3] };
        f32x4 v1 = { acc1[4*q+0], acc1[4*q+1], acc1[4*q+2], acc1[4*q+3] };
        *(f32x4*)&rb[wave][colLane][r0]      = v0;
        *(f32x4*)&rb[wave][32 + colLane][r0] = v1;
      }
    }
    __syncthreads();   // the only barrier per step

    // ---- reduce read (8x ds_read_b128) + 4x4 lane transpose + gates ----
    {
      const float (*rb)[64][36] = red[t & 1];
      f32x4 s = {};
      #pragma unroll
      for (int kw = 0; kw < 8; ++kw)
        s += *(const f32x4*)&rb[kw][lane][4 * wave];

      // 4x4 transpose across lane groups g = lane>>4 (components k = rows).
      // stage 1: xor 16 swaps g0<->k0; stage 2: xor 32 swaps g1<->k1.
      float a0 = s[0], a1 = s[1], a2 = s[2], a3 = s[3];
      const bool gb0 = (lane >> 4) & 1;
      const bool gb1 = (lane >> 5) & 1;
      {
        float s0 = gb0 ? a0 : a1;
        float s1 = gb0 ? a2 : a3;
        float r0 = __shfl_xor(s0, 16, 64);
        float r1 = __shfl_xor(s1, 16, 64);
        a0 = gb0 ? r0 : a0;  a1 = gb0 ? a1 : r0;
        a2 = gb0 ? r1 : a2;  a3 = gb0 ? a3 : r1;
      }
      {
        float s0 = gb1 ? a0 : a2;
        float s1 = gb1 ? a1 : a3;
        float r0 = __shfl_xor(s0, 32, 64);
        float r1 = __shfl_xor(s1, 32, 64);
        a0 = gb1 ? r0 : a0;  a1 = gb1 ? r1 : a1;
        a2 = gb1 ? a2 : r0;  a3 = gb1 ? a3 : r1;
      }
      // lane now owns row erow = 4*wave + (lane>>4); a0..a3 = gates 0..3
      const float fg = sigmoidf_(a0 + bias[0]);
      const float ig = sigmoidf_(a1 + bias[1]);
      const float gg = tanhf_(a2 + bias[2]);
      const float og = sigmoidf_(a3 + bias[3]);
      c_state = c_state * fg + ig * gg;
      const float hv = og * tanhf_(c_state);

      const unsigned h16 =
          (unsigned)__builtin_bit_cast(unsigned short, (f16)hv);
      const unsigned hi = (unsigned)__shfl_xor((int)h16, 1, 64);
      if ((lane & 1) == 0) {
        unsigned pk = h16 | (hi << 16);
        unsigned* p = (unsigned*)(hwr(t) + (long)erow * H_ + cbase + ej);
        st_agent_b32(p, pk);
      }
      wait_vm0();   // ack this wave's h stores
      if (lane == 0)
        st_agent_b32(myflag, (unsigned)(t + 1));
    }

    // ---- x-part of t+1 (after publish; never delays it) ----
    acc0 = f32x16{}; acc1 = f32x16{};
    if (t + 1 < T_) {
      const f16* xrow = xg + (long)arow * (T_ * IN_) + (long)(t + 1) * IN_
                           + 64 * wave + khalf;
      f16x8 xa[4];
      #pragma unroll
      for (int f = 0; f < 4; ++f) xa[f] = *(const f16x8*)(xrow + 16 * f);
      #pragma unroll
      for (int kf = 0; kf < 4; ++kf) {
        acc0 = __builtin_amdgcn_mfma_f32_32x32x16_f16(xa[kf], wf[kf],      acc0, 0, 0, 0);
        acc1 = __builtin_amdgcn_mfma_f32_32x32x16_f16(xa[kf], wf[12 + kf], acc1, 0, 0, 0);
      }
    }
  }
}

// out = h_T @ W_out + b_out. hT = base ptr to [g][32][1024] (gs = group stride).
__global__ __launch_bounds__(256) void lstm_out(
    const f16* __restrict__ hT, long gs, const f16* __restrict__ WoT,
    const float* __restrict__ bout, float* __restrict__ out) {
  const int wgid = blockIdx.x;
  const int rowT = wgid >> 5;
  const int colT = wgid & 31;
  const int tid  = threadIdx.x;
  const int wave = tid >> 6;
  const int lane = tid & 63;
  const int r16  = lane & 15;
  const int ksel = (lane >> 4) * 8;

  const int g = rowT >> 1;
  const f16* hrow = hT + (long)g * gs + (long)((rowT & 1) * 16 + r16) * H_;
  const f16* wrow = WoT + (long)(colT * 16 + r16) * H_;

  f32x4 acc = {};
  #pragma unroll
  for (int f = 0; f < 8; ++f) {
    f16x8 a  = *(const f16x8*)(hrow + 256 * wave + 32 * f + ksel);
    f16x8 bf = *(const f16x8*)(wrow + 256 * wave + 32 * f + ksel);
    acc = __builtin_amdgcn_mfma_f32_16x16x32_f16(a, bf, acc, 0, 0, 0);
  }

  __shared__ float red[4][16][20];
  #pragma unroll
  for (int r = 0; r < 4; ++r)
    red[wave][(lane >> 4) * 4 + r][lane & 15] = acc[r];
  __syncthreads();

  const int row = tid >> 4;
  const int col = tid & 15;
  float s = bout[colT * 16 + col];
  #pragma unroll
  for (int w = 0; w < 4; ++w) s += red[w][row][col];
  out[(long)(rowT * 16 + row) * OUT_ + colT * 16 + col] = s;
}

extern "C" void kernel_launch(void* const* d_in, const int* in_sizes, int n_in,
                              void* d_out, int out_size, void* d_ws, size_t ws_size,
                              hipStream_t stream) {
  const float* x    = (const float*)d_in[0];
  const float* W    = (const float*)d_in[1];
  const float* b    = (const float*)d_in[2];
  const float* Wout = (const float*)d_in[3];
  const float* bout = (const float*)d_in[4];
  float* out = (float*)d_out;

  if (ws_size < WS_SMALL) return;

  char* wsb = (char*)d_ws;
  f16* x16  = (f16*)(wsb + X16_OFF);
  f16* WoT  = (f16*)(wsb + WOT_OFF);
  unsigned* flags = (unsigned*)(wsb + FLG_OFF);

  lstm_prepass<<<1024, 256, 0, stream>>>(x, Wout, x16, WoT);

  if (ws_size >= WS_BIG) {
    // BIG: write-once history, cached consumer loads.
    f16* hbig = (f16*)(wsb + HBIG_OFF);
    hipMemsetAsync(wsb + HBIG_OFF, 0, 2 * 32 * H_ * sizeof(f16), stream); // h0
    hipMemsetAsync(wsb + FLG_OFF, 0, 4096, stream);                       // flags
    lstm_main<true><<<128, 512, 0, stream>>>(W, b, x16, hbig, flags);
    lstm_out<<<128, 256, 0, stream>>>(hbig + (long)T_ * 2 * 32 * H_,
                                      (long)32 * H_, WoT, bout, out);
  } else {
    // Fallback: small double-buffer, agent h loads.
    f16* hsm = (f16*)(wsb + HS_OFF);
    hipMemsetAsync(wsb + HS_OFF, 0, FLG_OFF + 4096 - HS_OFF, stream);
    lstm_main<false><<<128, 512, 0, stream>>>(W, b, x16, hsm, flags);
    lstm_out<<<128, 256, 0, stream>>>(hsm, (long)2 * 32 * H_, WoT, bout, out);
  }
}